// Round 1
// baseline (146.201 us; speedup 1.0000x reference)
//
#include <hip/hip_runtime.h>
#include <hip/hip_bf16.h>

// Fused causal attention block for MI355X (gfx950).
// Pipeline: cvt(x) | transpose(Wqkv) | transpose(Wo) -> GEMM1(qkv) -> attn -> GEMM2(out)
// All matmuls use v_mfma_f32_16x16x32_bf16 with f32 accumulation.
// Workspace usage: 28 MB (xb 4MB | WqkvT 6MB | WoT 2MB | qkv 12MB | y 4MB).

using u16 = unsigned short;
typedef __attribute__((ext_vector_type(8))) __bf16 bf16x8;      // 8 bf16 = 4 VGPR (MFMA A/B frag)
typedef __attribute__((ext_vector_type(8))) unsigned short u16x8;
typedef __attribute__((ext_vector_type(4))) float f32x4;        // MFMA C/D frag

__device__ __forceinline__ u16 f2bf(float f) {
  union { float f; unsigned u; } v; v.f = f;
  unsigned r = v.u + 0x7FFFu + ((v.u >> 16) & 1u);  // round-to-nearest-even
  return (u16)(r >> 16);
}

__device__ __forceinline__ void gload_lds16(const void* g, void* l) {
  __builtin_amdgcn_global_load_lds((const __attribute__((address_space(1))) void*)g,
                                   (__attribute__((address_space(3))) void*)l, 16, 0, 0);
}

__device__ __forceinline__ f32x4 mfma16(bf16x8 a, bf16x8 b, f32x4 c) {
  return __builtin_amdgcn_mfma_f32_16x16x32_bf16(a, b, c, 0, 0, 0);
}

// ---------------- f32 -> bf16 straight convert ----------------
__global__ __launch_bounds__(256) void cvt_bf16_kernel(const float* __restrict__ in,
                                                       u16* __restrict__ out, int n) {
  int i = (blockIdx.x * 256 + threadIdx.x) * 8;
  if (i >= n) return;
  float4 a = *(const float4*)(in + i);
  float4 b = *(const float4*)(in + i + 4);
  u16x8 r;
  r[0] = f2bf(a.x); r[1] = f2bf(a.y); r[2] = f2bf(a.z); r[3] = f2bf(a.w);
  r[4] = f2bf(b.x); r[5] = f2bf(b.y); r[6] = f2bf(b.z); r[7] = f2bf(b.w);
  *(u16x8*)(out + i) = r;
}

// ---------------- f32 [R][C] -> bf16 [C][R] transpose-convert ----------------
__global__ __launch_bounds__(256) void transpose_bf16_kernel(const float* __restrict__ in,
                                                             u16* __restrict__ out,
                                                             int R, int C) {
  __shared__ u16 tile[32][33];
  const int c0 = blockIdx.x * 32, r0 = blockIdx.y * 32;
  const int tx = threadIdx.x & 31, ty = threadIdx.x >> 5;
#pragma unroll
  for (int rr = ty; rr < 32; rr += 8)
    tile[rr][tx] = f2bf(in[(size_t)(r0 + rr) * C + (c0 + tx)]);
  __syncthreads();
#pragma unroll
  for (int rr = ty; rr < 32; rr += 8)
    out[(size_t)(c0 + rr) * R + (r0 + tx)] = tile[tx][rr];
}

// ---------------- bf16 GEMM, C[M][N] = A[M][K] * Bt[N][K]^T ----------------
// m97 structure: 128x128 tile, BK=32, 4 waves (2x2 of 64x64), global_load_lds w=16,
// 2-phase double buffer, one barrier per K-step.
template <typename OutT>
__global__ __launch_bounds__(256) void gemm_bt_kernel(const u16* __restrict__ A,
                                                      const u16* __restrict__ Bt,
                                                      OutT* __restrict__ C,
                                                      int M, int N, int K) {
  constexpr int BM = 128, BN = 128, BK = 32;
  __shared__ u16 As[2][BM * BK];
  __shared__ u16 Bs[2][BN * BK];
  const int tid = threadIdx.x;
  const int lane = tid & 63, wid = tid >> 6;
  const int l16 = lane & 15, l4 = lane >> 4;
  const int wr = (wid >> 1) * 64, wc = (wid & 1) * 64;
  const long bm = (long)blockIdx.x * BM, bn = (long)blockIdx.y * BN;

  f32x4 acc[4][4] = {};
  const int KT = K / BK;

  auto stage = [&](int buf, int kt) {
    const int k0 = kt * BK;
#pragma unroll
    for (int half = 0; half < 2; ++half) {
      int t = half * 256 + tid;
      int row = t >> 2, c8 = (t & 3) << 3;                 // 4 x 16B chunks / 64B row
      gload_lds16(A + (bm + row) * (size_t)K + k0 + c8, &As[buf][row * BK + c8]);
    }
#pragma unroll
    for (int half = 0; half < 2; ++half) {
      int t = half * 256 + tid;
      int row = t >> 2, c8 = (t & 3) << 3;
      gload_lds16(Bt + (bn + row) * (size_t)K + k0 + c8, &Bs[buf][row * BK + c8]);
    }
  };

  stage(0, 0);
  __syncthreads();  // drains vmcnt before barrier (compiler-emitted)
  int cur = 0;
  for (int kt = 0; kt < KT; ++kt) {
    if (kt + 1 < KT) stage(cur ^ 1, kt + 1);  // prefetch next K-tile into other buffer
    bf16x8 af[4], bfr[4];
#pragma unroll
    for (int m = 0; m < 4; ++m)   // A frag: row = l16, k-octet = l4
      af[m] = *(const bf16x8*)&As[cur][(wr + m * 16 + l16) * BK + l4 * 8];
#pragma unroll
    for (int n = 0; n < 4; ++n)   // B frag from Bt rows: col = l16, k-octet = l4
      bfr[n] = *(const bf16x8*)&Bs[cur][(wc + n * 16 + l16) * BK + l4 * 8];
#pragma unroll
    for (int m = 0; m < 4; ++m)
#pragma unroll
      for (int n = 0; n < 4; ++n)
        acc[m][n] = mfma16(af[m], bfr[n], acc[m][n]);
    __syncthreads();
    cur ^= 1;
  }

  // C/D layout: col = lane&15, row = (lane>>4)*4 + j  [verified m89/m91]
#pragma unroll
  for (int m = 0; m < 4; ++m) {
    const long row0 = bm + wr + m * 16 + l4 * 4;
#pragma unroll
    for (int n = 0; n < 4; ++n) {
      const long col = bn + wc + n * 16 + l16;
#pragma unroll
      for (int j = 0; j < 4; ++j) {
        float v = acc[m][n][j];
        if constexpr (sizeof(OutT) == 2)
          C[(row0 + j) * N + col] = (OutT)f2bf(v);
        else
          C[(row0 + j) * N + col] = (OutT)v;
      }
    }
  }
}

// ---------------- causal flash attention ----------------
// qkv: [T][3072] bf16 (Q at h*64, K at 1024+h*64, V at 2048+h*64), y: [T][1024] bf16.
// Block = 64 queries x 1 head, 4 waves (16 q-rows each); KV tiles of 64 keys.
__global__ __launch_bounds__(256) void attn_kernel(const u16* __restrict__ qkv,
                                                   u16* __restrict__ y) {
  constexpr int W = 3072, HD = 64;
  const int h = blockIdx.y;
  const int qt = (int)gridDim.x - 1 - (int)blockIdx.x;  // big blocks dispatch first
  const int q0 = qt * 64;
  const int tid = threadIdx.x, wid = tid >> 6, lane = tid & 63;
  const int l16 = lane & 15, l4 = lane >> 4;

  __shared__ u16 Ks[64 * 64];       // K tile [key][d], XOR-swizzled rows (128B rows)
  __shared__ u16 Vt[64][72];        // V^T tile [d][key], +8 pad (16B-aligned rows)
  __shared__ u16 Ps[4][16][72];     // per-wave P tile [qrow][key]

  // Q A-frags live in registers: A row = l16, k-octet = l4
  const u16* qrow = qkv + (size_t)(q0 + wid * 16 + l16) * W + h * HD;
  const bf16x8 qa0 = *(const bf16x8*)(qrow + l4 * 8);
  const bf16x8 qa1 = *(const bf16x8*)(qrow + 32 + l4 * 8);

  f32x4 o[4] = {};
  float mrow[4] = {-1e30f, -1e30f, -1e30f, -1e30f};
  float lrow[4] = {0.f, 0.f, 0.f, 0.f};

  for (int kv = 0; kv <= qt; ++kv) {
    const int k0 = kv * 64;
    __syncthreads();  // previous tile's LDS reads complete before overwrite

    // Stage K tile: linear LDS dest, pre-swizzled global source (rule 21).
    // Read side XORs byte bit4..6 with (row&7)<<4 so 64-lane ds_read_b128 is min-cycle.
#pragma unroll
    for (int half = 0; half < 2; ++half) {
      int t = half * 256 + tid;
      int row = t >> 3, chunk = t & 7;              // 8 x 16B chunks per 128B row
      int srcChunk = chunk ^ (row & 7);
      gload_lds16(qkv + (size_t)(k0 + row) * W + 1024 + h * HD + srcChunk * 8,
                  (u16*)Ks + t * 8);
    }
    // Stage V^T (register transpose; 64B-coalesced loads, scalar LDS writes)
    {
      int key = tid >> 2, d0 = (tid & 3) * 16;
      const u16* vsrc = qkv + (size_t)(k0 + key) * W + 2048 + h * HD + d0;
      u16x8 v0 = *(const u16x8*)(vsrc);
      u16x8 v1 = *(const u16x8*)(vsrc + 8);
#pragma unroll
      for (int i = 0; i < 8; ++i) Vt[d0 + i][key] = v0[i];
#pragma unroll
      for (int i = 0; i < 8; ++i) Vt[d0 + 8 + i][key] = v1[i];
    }
    __syncthreads();

    // S = Q K^T  (16 q-rows x 64 keys per wave); B frag: col(key)=l16, k-octet(d)=l4
    f32x4 s[4];
#pragma unroll
    for (int nb = 0; nb < 4; ++nb) {
      const int krow = nb * 16 + l16;
      const char* kbase = (const char*)Ks + krow * 128;
      const int swz = (krow & 7) << 4;
      bf16x8 kb0 = *(const bf16x8*)(kbase + ((l4 * 16) ^ swz));
      bf16x8 kb1 = *(const bf16x8*)(kbase + ((64 + l4 * 16) ^ swz));
      f32x4 z = {0.f, 0.f, 0.f, 0.f};
      z = mfma16(qa0, kb0, z);
      s[nb] = mfma16(qa1, kb1, z);
    }

    // scale + causal mask + online softmax (rows = l4*4+j, replicated over l16 group)
    float p[4][4];
    float rmax[4] = {-1e30f, -1e30f, -1e30f, -1e30f};
#pragma unroll
    for (int nb = 0; nb < 4; ++nb) {
      const int kcol = k0 + nb * 16 + l16;
#pragma unroll
      for (int j = 0; j < 4; ++j) {
        const int qr = q0 + wid * 16 + l4 * 4 + j;
        float v = s[nb][j] * 0.125f;
        v = (kcol <= qr) ? v : -1e30f;
        p[nb][j] = v;
        rmax[j] = fmaxf(rmax[j], v);
      }
    }
#pragma unroll
    for (int off = 1; off < 16; off <<= 1)
#pragma unroll
      for (int j = 0; j < 4; ++j)
        rmax[j] = fmaxf(rmax[j], __shfl_xor(rmax[j], off));

    float rsum[4];
#pragma unroll
    for (int j = 0; j < 4; ++j) {
      const float mnew = fmaxf(mrow[j], rmax[j]);
      const float sc = __expf(mrow[j] - mnew);   // first tile: exp(-inf)=0
      mrow[j] = mnew;
      lrow[j] *= sc;
#pragma unroll
      for (int nb = 0; nb < 4; ++nb) o[nb][j] *= sc;
      rsum[j] = 0.f;
#pragma unroll
      for (int nb = 0; nb < 4; ++nb) {
        const float e = __expf(p[nb][j] - mnew);  // masked -> exp(-1e30)=0
        p[nb][j] = e;
        rsum[j] += e;
      }
    }
#pragma unroll
    for (int off = 1; off < 16; off <<= 1)
#pragma unroll
      for (int j = 0; j < 4; ++j)
        rsum[j] += __shfl_xor(rsum[j], off);
#pragma unroll
    for (int j = 0; j < 4; ++j) lrow[j] += rsum[j];

    // P: C-layout regs -> per-wave LDS -> A-layout frags (intra-wave, auto lgkmcnt)
#pragma unroll
    for (int nb = 0; nb < 4; ++nb)
#pragma unroll
      for (int j = 0; j < 4; ++j)
        Ps[wid][l4 * 4 + j][nb * 16 + l16] = f2bf(p[nb][j]);
    const bf16x8 pa0 = *(const bf16x8*)&Ps[wid][l16][l4 * 8];
    const bf16x8 pa1 = *(const bf16x8*)&Ps[wid][l16][32 + l4 * 8];

    // O += P V : B frag from Vt rows: col(d)=l16(+16nb), k-octet(key)=l4
#pragma unroll
    for (int nb = 0; nb < 4; ++nb) {
      bf16x8 vb0 = *(const bf16x8*)&Vt[nb * 16 + l16][l4 * 8];
      bf16x8 vb1 = *(const bf16x8*)&Vt[nb * 16 + l16][32 + l4 * 8];
      o[nb] = mfma16(pa0, vb0, o[nb]);
      o[nb] = mfma16(pa1, vb1, o[nb]);
    }
  }

  // epilogue: O /= l, write bf16 y[T][1024]
#pragma unroll
  for (int j = 0; j < 4; ++j) {
    const float inv = 1.0f / lrow[j];
    u16* yr = y + (size_t)(q0 + wid * 16 + l4 * 4 + j) * 1024 + h * HD;
#pragma unroll
    for (int nb = 0; nb < 4; ++nb)
      yr[nb * 16 + l16] = f2bf(o[nb][j] * inv);
  }
}

// ---------------- launch ----------------
extern "C" void kernel_launch(void* const* d_in, const int* in_sizes, int n_in,
                              void* d_out, int out_size, void* d_ws, size_t ws_size,
                              hipStream_t stream) {
  constexpr int T = 2048, D = 1024;
  const float* x    = (const float*)d_in[0];   // [T][D]
  const float* Wqkv = (const float*)d_in[1];   // [D][3D]
  const float* Wo   = (const float*)d_in[2];   // [D][D]
  float* out = (float*)d_out;                  // [T][D] f32

  u16* xb    = (u16*)d_ws;                     // [T][D]
  u16* WqkvT = xb + (size_t)T * D;             // [3D][D]
  u16* WoT   = WqkvT + (size_t)3 * D * D;      // [D][D]
  u16* qkv   = WoT + (size_t)D * D;            // [T][3D]
  u16* yb    = qkv + (size_t)T * 3 * D;        // [T][D]   (total 28 MB)

  cvt_bf16_kernel<<<(T * D) / (256 * 8), 256, 0, stream>>>(x, xb, T * D);
  transpose_bf16_kernel<<<dim3(3 * D / 32, D / 32), 256, 0, stream>>>(Wqkv, WqkvT, D, 3 * D);
  transpose_bf16_kernel<<<dim3(D / 32, D / 32), 256, 0, stream>>>(Wo, WoT, D, D);

  gemm_bt_kernel<u16><<<dim3(T / 128, 3 * D / 128), 256, 0, stream>>>(xb, WqkvT, qkv, T, 3 * D, D);
  attn_kernel<<<dim3(T / 64, 16), 256, 0, stream>>>(qkv, yb);
  gemm_bt_kernel<float><<<dim3(T / 128, D / 128), 256, 0, stream>>>(yb, WoT, out, T, D, D);
}